// Round 13
// baseline (3003.826 us; speedup 1.0000x reference)
//
#include <hip/hip_runtime.h>
#include <hip/hip_bf16.h>
#include <math.h>
#include <stdint.h>

// Problem constants
#define CCH   192      // channels
#define HWD   224      // H = W = 224
#define NWIN  8192     // 8 * 32 * 32 windows
#define NPIX  49       // 7*7 pixels per window
#define KDIM  192      // GEMM1 K
#define NHEAD 6
#define ROWB  (KDIM * 2)   // 384 bytes per LDS row
#define MULQ  0.2550348616845977f   // 32^-0.5 * log2(e), folded into W_q/b_q

typedef __bf16 bf16x8 __attribute__((ext_vector_type(8)));
typedef __bf16 bf16x2 __attribute__((ext_vector_type(2)));
typedef float  f32x4  __attribute__((ext_vector_type(4)));

// Convert W (384x192 f32) to bf16 pre-swizzled into MFMA B-fragment order,
// with scale*log2e pre-folded into the q half (rows 0..191).
// out[((ng*6 + kk)*4 + lg)*128 + lr*8 + e] = W[(ng*16+lr)*192 + kk*32+lg*8+e]
// Also writes the (scaled) bias as f32 at wbf+73728.
__global__ void wconv_kernel(const float* __restrict__ w,
                             const float* __restrict__ bq,
                             uint16_t* __restrict__ wbf) {
    int o = blockIdx.x * 256 + threadIdx.x;
    if (o >= 384 * 192) return;
    if (o < 384) {
        float bb = bq[o];
        if (o < 192) bb *= MULQ;
        ((float*)(wbf + 384 * 192))[o] = bb;
    }
    int e  = o & 7;
    int t  = o >> 3;
    int lr = t & 15;  t >>= 4;
    int lg = t & 3;   t >>= 2;
    int kk = t % 6;
    int ng = t / 6;
    int col  = ng * 16 + lr;
    int kcol = kk * 32 + lg * 8 + e;
    float wv = w[col * KDIM + kcol];
    if (col < 192) wv *= MULQ;            // q half pre-scaled
    __bf16 v = (__bf16)wv;
    wbf[o] = __builtin_bit_cast(uint16_t, v);
}

// 256 blocks (1 per CU), 1024 threads = 16 waves. Block owns window-row
// (b, wh) and loops its 32 windows. W fragments (72 VGPR) + bias resident in
// registers for the whole block -> phase 2 is ds_read+MFMA only (the 18
// per-window W loads were the serializer: at 64-reg budget the compiler
// couldn't hoist them -> ~30 serial L2 latencies per wave per window;
// occupancy couldn't hide it, which is why R4(45% occ) == R10(88% occ)).
// x gather for window j+1 prefetched during phase 4 of window j.
// LDS: X + Q + K = 3 x 49x192 bf16 = 56448 B. 128-reg budget (4 w/EU).
__global__ __launch_bounds__(1024, 4)
void attn_win_kernel(const float* __restrict__ x,
                     const uint16_t* __restrict__ wbf,
                     float* __restrict__ out) {
    __shared__ uint16_t ldsX[NPIX * KDIM];   // xw tile of current window
    __shared__ uint16_t ldsQ[NPIX * KDIM];   // q
    __shared__ uint16_t ldsK[NPIX * KDIM];   // k

    const int tid  = threadIdx.x;
    const int wave = tid >> 6;   // 0..15
    const int l    = tid & 63;
    const int lg   = l >> 4;     // 0..3
    const int lr   = l & 15;     // 0..15

    // block -> (image, window-row). XCD i streams image i (256 = 8 XCD * 32).
    const int b   = (int)blockIdx.x & 7;
    const int wh  = (int)blockIdx.x >> 3;    // 0..31
    const int h0  = wh * 7;

    // ---- Persistent per-wave state (live whole block) ----
    const int mp = wave & 1;     // GEMM1 row half
    const int cg = wave >> 1;    // GEMM1 col group (48 cols)

    // W fragments: 18 x bf16x8 = 72 VGPR, loaded once.
    bf16x8 wfr[18];
    #pragma unroll
    for (int kk = 0; kk < 6; ++kk)
        #pragma unroll
        for (int nt = 0; nt < 3; ++nt)
            wfr[kk * 3 + nt] = *(const bf16x8*)(
                wbf + (((cg * 3 + nt) * 6 + kk) * 4 + lg) * 128 + lr * 8);

    // bias (scaled) per nt
    const float* biasp = (const float*)(wbf + 384 * 192);
    float bias0[3];
    #pragma unroll
    for (int nt = 0; nt < 3; ++nt)
        bias0[nt] = biasp[cg * 48 + nt * 16 + lr];

    // gather geometry: lane = pixel, wave owns 12 channels
    const int pr = (l * 37) >> 8;            // l / 7 for l in [0,49)
    const int ps = l - pr * 7;
    const float* xlane = x + (size_t)(b * CCH + wave * 12) * (HWD * HWD)
                           + (size_t)(h0 + pr) * HWD + ps;   // + c*HW2 + ww*7
    const uint32_t rb   = (uint32_t)(l * ROWB + wave * 24);
    const uint32_t swz  = (uint32_t)((l & 7) << 4);
    const bool glane = (l < NPIX);

    // phase-4 constants
    const int qt    = wave & 3;
    const int qrow  = qt * 16 + lr;
    const int qrc   = qrow > 48 ? 48 : qrow;
    const uint32_t qswz = (uint32_t)((qrc & 7) << 4);
    const int h1 = wave >> 2;                // first head (0..3)

    // ---- Prologue: issue gather for window 0
    float g[12];
    if (glane) {
        #pragma unroll
        for (int c = 0; c < 12; ++c)
            g[c] = xlane[(size_t)c * (HWD * HWD)];
    }

    for (int j = 0; j < 32; ++j) {
        // ---- xwrite: g -> ldsX (waits the in-flight gather; covered by
        // previous window's phase 4)
        if (glane) {
            #pragma unroll
            for (int c = 0; c < 12; c += 2) {
                bf16x2 p = { (__bf16)g[c], (__bf16)g[c + 1] };
                *(uint32_t*)((char*)ldsX + ((rb + (uint32_t)(c * 2)) ^ swz)) =
                    __builtin_bit_cast(uint32_t, p);
            }
        }
        __syncthreads();   // B0: X complete (also: phase4(j-1) Q/K reads done)

        // ---- Phase 2: GEMM1 from LDS + resident W (no global loads)
        f32x4 acc[2][3];
        #pragma unroll
        for (int nt = 0; nt < 3; ++nt) {
            float bb = bias0[nt];
            #pragma unroll
            for (int mt = 0; mt < 2; ++mt)
                acc[mt][nt] = f32x4{bb, bb, bb, bb};
        }
        #pragma unroll
        for (int kk = 0; kk < 6; ++kk) {
            bf16x8 afr[2];
            #pragma unroll
            for (int mt = 0; mt < 2; ++mt) {
                int row = mp * 32 + mt * 16 + lr;
                if (row > 48) row = 48;               // clamp: no pad rows
                int byte = (row * ROWB + kk * 64 + lg * 16) ^ ((row & 7) << 4);
                afr[mt] = *(const bf16x8*)((const char*)ldsX + byte);
            }
            #pragma unroll
            for (int nt = 0; nt < 3; ++nt)
                #pragma unroll
                for (int mt = 0; mt < 2; ++mt)
                    acc[mt][nt] = __builtin_amdgcn_mfma_f32_16x16x32_bf16(
                        afr[mt], wfr[kk * 3 + nt], acc[mt][nt], 0, 0, 0);
        }
        __syncthreads();   // B1: X reads done (next xwrite may overwrite)

        // ---- Phase 3: q -> ldsQ, k -> ldsK (bias/scale already in acc)
        {
            const bool isq = (cg < 4);
            uint16_t* dst = isq ? ldsQ : ldsK;
            #pragma unroll
            for (int nt = 0; nt < 3; ++nt) {
                int colW = cg * 48 + nt * 16 + lr;    // 0..383
                int jj = isq ? colW : (colW - 192);
                #pragma unroll
                for (int mt = 0; mt < 2; ++mt) {
                    #pragma unroll
                    for (int r = 0; r < 4; ++r) {
                        int row = mp * 32 + mt * 16 + lg * 4 + r;
                        if (row < NPIX) {
                            __bf16 bv = (__bf16)acc[mt][nt][r];
                            *(__bf16*)((char*)dst +
                                ((row * ROWB + jj * 2) ^ ((row & 7) << 4))) = bv;
                        }
                    }
                }
            }
        }
        __syncthreads();   // B2: q/k visible

        // ---- Issue gather for window j+1 (drains under phase 4 + next xwrite)
        if (j < 31 && glane) {
            const float* xpn = xlane + (size_t)((j + 1) * 7);
            #pragma unroll
            for (int c = 0; c < 12; ++c)
                g[c] = xpn[(size_t)c * (HWD * HWD)];
        }

        // ---- Phase 4: swapped-operand GEMM2 + lane-local softmax + stores.
        // Lane (lg,lr) of wave (qt) holds S[qrow=qt*16+lr][k = nt2*16+lg*4+r].
        float* outw = out + (size_t)((b * 32 + wh) * 32 + j) * (NHEAD * NPIX * NPIX);

        auto do_head = [&](int h) {
            const bf16x8 qfr = *(const bf16x8*)((const char*)ldsQ +
                (((uint32_t)(qrc * ROWB + h * 64 + lg * 16)) ^ qswz));

            float v[16];
            #pragma unroll
            for (int nt2 = 0; nt2 < 4; ++nt2) {
                int krow = nt2 * 16 + lr;
                if (krow > 48) krow = 48;             // clamp (masked later)
                const bf16x8 kfr = *(const bf16x8*)((const char*)ldsK +
                    (((uint32_t)(krow * ROWB + h * 64 + lg * 16)) ^ ((krow & 7) << 4)));
                f32x4 p = __builtin_amdgcn_mfma_f32_16x16x32_bf16(
                    kfr, qfr, f32x4{0.f, 0.f, 0.f, 0.f}, 0, 0, 0);
                #pragma unroll
                for (int r = 0; r < 4; ++r) {
                    int k = nt2 * 16 + lg * 4 + r;
                    v[nt2 * 4 + r] = (k < NPIX) ? p[r] : -INFINITY;
                }
            }

            float m = v[0];
            #pragma unroll
            for (int i = 1; i < 16; ++i) m = fmaxf(m, v[i]);
            m = fmaxf(m, __shfl_xor(m, 16, 64));
            m = fmaxf(m, __shfl_xor(m, 32, 64));

            float sum = 0.f;
            #pragma unroll
            for (int i = 0; i < 16; ++i) {
                v[i] = exp2f(v[i] - m);    // logits already in log2 domain
                sum += v[i];
            }
            sum += __shfl_xor(sum, 16, 64);
            sum += __shfl_xor(sum, 32, 64);
            const float inv = __fdividef(1.0f, sum);

            if (qrow < NPIX) {
                float* orow = outw + h * (NPIX * NPIX) + qrow * NPIX;
                #pragma unroll
                for (int nt2 = 0; nt2 < 3; ++nt2)
                    #pragma unroll
                    for (int r = 0; r < 4; ++r)
                        orow[nt2 * 16 + lg * 4 + r] = v[nt2 * 4 + r] * inv;
                if (lg == 0) orow[48] = v[12] * inv;
            }
        };

        do_head(h1);
        if (wave < 8) do_head(h1 + 4);   // heads 4,5
    }
}

extern "C" void kernel_launch(void* const* d_in, const int* in_sizes, int n_in,
                              void* d_out, int out_size, void* d_ws, size_t ws_size,
                              hipStream_t stream) {
    const float* x  = (const float*)d_in[0];
    const float* W  = (const float*)d_in[1];
    const float* bq = (const float*)d_in[2];
    float* out = (float*)d_out;
    uint16_t* wbf = (uint16_t*)d_ws;   // 147456 B swizzled W + 1536 B bias f32

    wconv_kernel<<<(384 * 192 + 255) / 256, 256, 0, stream>>>(W, bq, wbf);
    attn_win_kernel<<<256, 1024, 0, stream>>>(x, wbf, out);
}

// Round 14
// 1114.780 us; speedup vs baseline: 2.6945x; 2.6945x over previous
//
#include <hip/hip_runtime.h>
#include <hip/hip_bf16.h>
#include <math.h>
#include <stdint.h>

// Problem constants
#define CCH   192      // channels
#define HWD   224      // H = W = 224
#define NWIN  8192     // 8 * 32 * 32 windows
#define NPIX  49       // 7*7 pixels per window
#define KDIM  192      // GEMM1 K
#define NHEAD 6
#define ROWB  (KDIM * 2)   // 384 bytes per LDS row
#define MULQ  0.2550348616845977f   // 32^-0.5 * log2(e), folded into W_q/b_q

typedef __bf16 bf16x8 __attribute__((ext_vector_type(8)));
typedef __bf16 bf16x2 __attribute__((ext_vector_type(2)));
typedef float  f32x4  __attribute__((ext_vector_type(4)));

// Convert W (384x192 f32) to bf16 pre-swizzled into MFMA B-fragment order,
// with scale*log2e pre-folded into the q half. Bias (scaled) at wbf+73728.
__global__ void wconv_kernel(const float* __restrict__ w,
                             const float* __restrict__ bq,
                             uint16_t* __restrict__ wbf) {
    int o = blockIdx.x * 256 + threadIdx.x;
    if (o >= 384 * 192) return;
    if (o < 384) {
        float bb = bq[o];
        if (o < 192) bb *= MULQ;
        ((float*)(wbf + 384 * 192))[o] = bb;
    }
    int e  = o & 7;
    int t  = o >> 3;
    int lr = t & 15;  t >>= 4;
    int lg = t & 3;   t >>= 2;
    int kk = t % 6;
    int ng = t / 6;
    int col  = ng * 16 + lr;
    int kcol = kk * 32 + lg * 8 + e;
    float wv = w[col * KDIM + kcol];
    if (col < 192) wv *= MULQ;            // q half pre-scaled
    __bf16 v = (__bf16)wv;
    wbf[o] = __builtin_bit_cast(uint16_t, v);
}

// ABLATION build of the R11 kernel (343 us best).
// V=0 full | V=1 no stores | V=2 no softmax | V=3 phases 1-3 | V=4 phase 1.
// All variants launched full-grid; V0 runs LAST so d_out ends correct.
// asm volatile keep-alives prevent upstream DCE (rule #17).
template<int V>
__global__ __launch_bounds__(1024, 8)
void attn_ab(const float* __restrict__ x,
             const uint16_t* __restrict__ wbf,
             float* __restrict__ out) {
    __shared__ uint16_t ldsA[NPIX * KDIM];   // xw tile, later q
    __shared__ uint16_t ldsB[NPIX * KDIM];   // k

    const int tid  = threadIdx.x;
    const int wave = tid >> 6;   // 0..15
    const int l    = tid & 63;
    const int lg   = l >> 4;     // 0..3
    const int lr   = l & 15;     // 0..15

    const int win = ((blockIdx.x & 7) << 10) | (blockIdx.x >> 3);
    const int b   = win >> 10;
    const int wh  = (win >> 5) & 31;
    const int ww  = win & 31;
    const int h0 = wh * 7, w0 = ww * 7;

    const float* bias = (const float*)(wbf + 384 * 192);

    // ---- Phase 1: gather x window -> ldsA (bf16, XOR-swizzled rows)
    if (l < NPIX) {
        int r = (l * 37) >> 8;
        int s = l - r * 7;
        const float* xp = x + (size_t)(b * CCH + wave * 12) * (HWD * HWD)
                            + (h0 + r) * HWD + (w0 + s);
        float g[12];
        #pragma unroll
        for (int c = 0; c < 12; ++c)
            g[c] = xp[(size_t)c * (HWD * HWD)];
        const uint32_t rb  = (uint32_t)(l * ROWB + wave * 24);
        const uint32_t swz = (uint32_t)((l & 7) << 4);
        #pragma unroll
        for (int c = 0; c < 12; c += 2) {
            bf16x2 p = { (__bf16)g[c], (__bf16)g[c + 1] };
            uint32_t byte = (rb + (uint32_t)(c * 2)) ^ swz;
            *(uint32_t*)((char*)ldsA + byte) = __builtin_bit_cast(uint32_t, p);
        }
    }
    __syncthreads();

    if constexpr (V == 4) {
        uint32_t dx = *(const uint32_t*)((const char*)ldsA + tid * 4);
        asm volatile("" :: "v"(dx));
        return;
    }

    // ---- Phase 2: GEMM1 (+bias via acc init)
    const int mp = wave & 1;
    const int cg = wave >> 1;
    f32x4 acc[2][3];
    #pragma unroll
    for (int nt = 0; nt < 3; ++nt) {
        float bb = bias[cg * 48 + nt * 16 + lr];
        #pragma unroll
        for (int mt = 0; mt < 2; ++mt)
            acc[mt][nt] = f32x4{bb, bb, bb, bb};
    }
    #pragma unroll
    for (int kk = 0; kk < 6; ++kk) {
        bf16x8 afr[2];
        #pragma unroll
        for (int mt = 0; mt < 2; ++mt) {
            int row = mp * 32 + mt * 16 + lr;
            if (row > 48) row = 48;
            int byte = (row * ROWB + kk * 64 + lg * 16) ^ ((row & 7) << 4);
            afr[mt] = *(const bf16x8*)((const char*)ldsA + byte);
        }
        #pragma unroll
        for (int nt = 0; nt < 3; ++nt) {
            int ng = cg * 3 + nt;
            bf16x8 bfr = *(const bf16x8*)(wbf + ((ng * 6 + kk) * 4 + lg) * 128 + lr * 8);
            #pragma unroll
            for (int mt = 0; mt < 2; ++mt)
                acc[mt][nt] = __builtin_amdgcn_mfma_f32_16x16x32_bf16(
                    afr[mt], bfr, acc[mt][nt], 0, 0, 0);
        }
    }
    __syncthreads();

    // ---- Phase 3: q -> ldsA, k -> ldsB
    {
        const bool isq = (cg < 4);
        uint16_t* dst = isq ? ldsA : ldsB;
        #pragma unroll
        for (int nt = 0; nt < 3; ++nt) {
            int colW = cg * 48 + nt * 16 + lr;
            int jj = isq ? colW : (colW - 192);
            #pragma unroll
            for (int mt = 0; mt < 2; ++mt) {
                #pragma unroll
                for (int r = 0; r < 4; ++r) {
                    int row = mp * 32 + mt * 16 + lg * 4 + r;
                    if (row < NPIX) {
                        __bf16 bv = (__bf16)acc[mt][nt][r];
                        *(__bf16*)((char*)dst +
                            ((row * ROWB + jj * 2) ^ ((row & 7) << 4))) = bv;
                    }
                }
            }
        }
    }
    __syncthreads();

    if constexpr (V == 3) {
        uint32_t dq = *(const uint32_t*)((const char*)ldsA + tid * 4);
        uint32_t dk = *(const uint32_t*)((const char*)ldsB + tid * 4);
        asm volatile("" :: "v"(dq), "v"(dk));
        return;
    }

    // ---- Phase 4: swapped-operand GEMM2 + softmax + stores (per variant)
    float* outw = out + (size_t)win * (NHEAD * NPIX * NPIX);
    const int qt    = wave & 3;
    const int qrow  = qt * 16 + lr;
    const int qrc   = qrow > 48 ? 48 : qrow;
    const uint32_t qswz = (uint32_t)((qrc & 7) << 4);

    auto do_head = [&](int h) {
        const bf16x8 qfr = *(const bf16x8*)((const char*)ldsA +
            (((uint32_t)(qrc * ROWB + h * 64 + lg * 16)) ^ qswz));

        float v[16];
        #pragma unroll
        for (int nt2 = 0; nt2 < 4; ++nt2) {
            int krow = nt2 * 16 + lr;
            if (krow > 48) krow = 48;
            const bf16x8 kfr = *(const bf16x8*)((const char*)ldsB +
                (((uint32_t)(krow * ROWB + h * 64 + lg * 16)) ^ ((krow & 7) << 4)));
            f32x4 p = __builtin_amdgcn_mfma_f32_16x16x32_bf16(
                kfr, qfr, f32x4{0.f, 0.f, 0.f, 0.f}, 0, 0, 0);
            #pragma unroll
            for (int r = 0; r < 4; ++r) {
                int k = nt2 * 16 + lg * 4 + r;
                v[nt2 * 4 + r] = (k < NPIX) ? p[r] : -INFINITY;
            }
        }

        float inv;
        if constexpr (V != 2) {
            float m = v[0];
            #pragma unroll
            for (int i = 1; i < 16; ++i) m = fmaxf(m, v[i]);
            m = fmaxf(m, __shfl_xor(m, 16, 64));
            m = fmaxf(m, __shfl_xor(m, 32, 64));
            float sum = 0.f;
            #pragma unroll
            for (int i = 0; i < 16; ++i) {
                v[i] = exp2f(v[i] - m);
                sum += v[i];
            }
            sum += __shfl_xor(sum, 16, 64);
            sum += __shfl_xor(sum, 32, 64);
            inv = __fdividef(1.0f, sum);
        } else {
            inv = 1.0f;   // V2: no softmax, store raw logits
        }

        if constexpr (V == 1) {
            asm volatile("" :: "v"(inv));   // keep whole chain, skip stores
        } else {
            if (qrow < NPIX) {
                float* orow = outw + h * (NPIX * NPIX) + qrow * NPIX;
                #pragma unroll
                for (int nt2 = 0; nt2 < 3; ++nt2)
                    #pragma unroll
                    for (int r = 0; r < 4; ++r)
                        orow[nt2 * 16 + lg * 4 + r] = v[nt2 * 4 + r] * inv;
                if (lg == 0) orow[48] = v[12] * inv;
            }
        }
    };

    const int h1 = wave >> 2;
    do_head(h1);
    if (wave < 8) do_head(h1 + 4);
}

extern "C" void kernel_launch(void* const* d_in, const int* in_sizes, int n_in,
                              void* d_out, int out_size, void* d_ws, size_t ws_size,
                              hipStream_t stream) {
    const float* x  = (const float*)d_in[0];
    const float* W  = (const float*)d_in[1];
    const float* bq = (const float*)d_in[2];
    float* out = (float*)d_out;
    uint16_t* wbf = (uint16_t*)d_ws;   // 147456 B swizzled W + 1536 B bias f32

    wconv_kernel<<<(384 * 192 + 255) / 256, 256, 0, stream>>>(W, bq, wbf);
    // Ablation probes (garbage/partial writes to d_out are overwritten by V0):
    attn_ab<4><<<NWIN, 1024, 0, stream>>>(x, wbf, out);
    attn_ab<3><<<NWIN, 1024, 0, stream>>>(x, wbf, out);
    attn_ab<2><<<NWIN, 1024, 0, stream>>>(x, wbf, out);
    attn_ab<1><<<NWIN, 1024, 0, stream>>>(x, wbf, out);
    // Full kernel LAST -> d_out correct.
    attn_ab<0><<<NWIN, 1024, 0, stream>>>(x, wbf, out);
}